// Round 6
// baseline (33.675 us; speedup 1.0000x reference)
//
#include <hip/hip_runtime.h>

// Problem constants
#define NB 64
#define NL 128
#define NQ 128
#define NE 16384

// ws float layout
#define WS_W    0          // [i][j] row-major fp32 W (edge-weight scatter target)
#define WS_TW   16384      // total weight
#define WS_NUM  16385      // numerator accumulator
// ws ushort layout (bf16 operand arrays), offsets in ushorts from ws base
#define US_ATB  32776                    // [q][p] A_fid^T bf16, 16384 ushorts
#define US_PB   (US_ATB + 16384)         // [b][i][k] P bf16 plain, 64*16384
#define US_PTB  (US_PB + NB * 16384)     // [b][q][j] P bf16 transposed, 64*16384

using short8 = __attribute__((ext_vector_type(8))) short;  // 8 bf16
using f32x4  = __attribute__((ext_vector_type(4))) float;

// fp32 -> bf16 bits, round-to-nearest-even
__device__ inline unsigned short f2bf(float f) {
    const unsigned u = __float_as_uint(f);
    return (unsigned short)((u + 0x7fffu + ((u >> 16) & 1u)) >> 16);
}

__device__ inline short8 pack8(float4 a, float4 b) {
    short8 r;
    r[0] = f2bf(a.x); r[1] = f2bf(a.y); r[2] = f2bf(a.z); r[3] = f2bf(a.w);
    r[4] = f2bf(b.x); r[5] = f2bf(b.y); r[6] = f2bf(b.z); r[7] = f2bf(b.w);
    return r;
}

// ---------------------------------------------------------------------------
// prep, grid 128 x 256:
//  blocks 0..63  : b = blk. Convert P[b] to bf16 plain (PB) and, via LDS
//                  transpose tile, bf16 transposed (PTB[q][j] = P[j][q]).
//  blocks 64..127: build ATB[q][p] bf16, scatter edge weights into fp32 W
//                  (row-major), block-reduce total weight.
// ---------------------------------------------------------------------------
__global__ __launch_bounds__(256) void prep_kernel(const float* __restrict__ P,
                                                   const float* __restrict__ dhw,
                                                   const float* __restrict__ derr,
                                                   const int* __restrict__ pairs,
                                                   const float* __restrict__ wts,
                                                   float* __restrict__ ws) {
    const int t = threadIdx.x;
    unsigned short* us = (unsigned short*)ws;

    if (blockIdx.x < 64) {
        const int b = blockIdx.x;
        const float* __restrict__ Pb = P + b * 16384;
        unsigned short* __restrict__ PBb  = us + US_PB  + b * 16384;
        unsigned short* __restrict__ PTBb = us + US_PTB + b * 16384;

        __shared__ unsigned short T[128 * 132];   // row stride 132 (pad)

        // Load rows (coalesced float4), emit plain bf16, stage LDS tile
        #pragma unroll
        for (int r = 0; r < 16; ++r) {
            const int f = t + 256 * r;            // float4 idx [0,4096)
            const float4 v = ((const float4*)Pb)[f];
            ushort4 u;
            u.x = f2bf(v.x); u.y = f2bf(v.y); u.z = f2bf(v.z); u.w = f2bf(v.w);
            ((ushort4*)PBb)[f] = u;               // coalesced 8B stores
            const int i = f >> 5, c = (f & 31) * 4;
            *(ushort4*)&T[i * 132 + c] = u;       // 2 lanes/bank: free
        }
        __syncthreads();

        // Emit transposed: PTB[q][j]; lanes span q -> conflict-free LDS reads
        #pragma unroll
        for (int r = 0; r < 8; ++r) {
            const int o    = t + 256 * r;         // short8 idx [0,2048)
            const int q    = o & 127;
            const int j0   = (o >> 7) * 8;
            short8 rd;
            #pragma unroll
            for (int d = 0; d < 8; ++d)
                rd[d] = (short)T[(j0 + d) * 132 + q];
            *(short8*)&PTBb[q * 128 + j0] = rd;
        }
    } else {
        const int idx = (blockIdx.x - 64) * 256 + t;   // [0, 16384)

        {   // ATB[q*128+p] = bf16( (dhw[p,q]==1) * max(1-derr[p,q],0) )
            const float hw = dhw[idx];
            const float er = derr[idx];
            const float a  = (hw == 1.0f) ? fmaxf(1.0f - er, 0.f) : 0.f;
            const int p = idx >> 7, q = idx & 127;
            us[US_ATB + q * 128 + p] = f2bf(a);
        }

        const int i = pairs[2 * idx];
        const int j = pairs[2 * idx + 1];
        const float w = wts[idx];
        atomicAdd(&ws[WS_W + i * 128 + j], w);

        float s = w;
        #pragma unroll
        for (int off = 32; off; off >>= 1) s += __shfl_down(s, off, 64);
        __shared__ float red[4];
        const int lane = t & 63, wv = t >> 6;
        if (lane == 0) red[wv] = s;
        __syncthreads();
        if (t == 0)
            atomicAdd(&ws[WS_TW], red[0] + red[1] + red[2] + red[3]);
    }
}

// ---------------------------------------------------------------------------
// batch (MFMA): block = (b, 16-row i-tile); 512 blocks x 512 threads (8 waves,
// wave wv owns q-tile wv). Per wave:
//   accG = sum_k mfma(Wfrag(fp32->bf16), PTfrag)   -> G = W * P_b
//   accY = sum_k mfma(Pfrag, ATfrag)               -> Y = P_b * A
//   s   += <accG, accY>  (C-layout invariant)
// All operand loads contiguous 16B, L2/L3-hot. No LDS staging, no barriers
// until the final reduce.
// ---------------------------------------------------------------------------
__global__ __launch_bounds__(512, 4) void batch_kernel(const float* __restrict__ ws_c,
                                                       float* __restrict__ ws) {
    const int blk = blockIdx.x;            // 512 = 64 b * 8 i-tiles
    const int b   = blk >> 3;
    const int i0  = (blk & 7) * 16;
    const unsigned short* us = (const unsigned short*)ws_c;
    const unsigned short* __restrict__ PBb  = us + US_PB  + b * 16384;
    const unsigned short* __restrict__ PTBb = us + US_PTB + b * 16384;
    const unsigned short* __restrict__ ATB  = us + US_ATB;

    const int t    = threadIdx.x;
    const int wv   = t >> 6;               // 0..7 -> q-tile
    const int lane = t & 63;
    const int mrow = i0 + (lane & 15);
    const int kb   = (lane >> 4) * 8;
    const int ncol = wv * 16 + (lane & 15);

    const float* __restrict__ Wrow = ws_c + WS_W + mrow * 128;

    f32x4 accG = {0.f, 0.f, 0.f, 0.f};
    f32x4 accY = {0.f, 0.f, 0.f, 0.f};
    #pragma unroll
    for (int kk = 0; kk < 4; ++kk) {
        const int k0 = kk * 32 + kb;
        const short8 wa = pack8(*(const float4*)&Wrow[k0],
                                *(const float4*)&Wrow[k0 + 4]);
        const short8 gb = *(const short8*)&PTBb[ncol * 128 + k0];
        const short8 pa = *(const short8*)&PBb[mrow * 128 + k0];
        const short8 yb = *(const short8*)&ATB[ncol * 128 + k0];
        accG = __builtin_amdgcn_mfma_f32_16x16x32_bf16(wa, gb, accG, 0, 0, 0);
        accY = __builtin_amdgcn_mfma_f32_16x16x32_bf16(pa, yb, accY, 0, 0, 0);
    }

    float s = accG[0] * accY[0] + accG[1] * accY[1]
            + accG[2] * accY[2] + accG[3] * accY[3];

    // Block reduce, one atomic per block
    #pragma unroll
    for (int off = 32; off; off >>= 1) s += __shfl_down(s, off, 64);
    __shared__ float red[8];
    if (lane == 0) red[wv] = s;
    __syncthreads();
    if (t == 0) {
        float acc = 0.f;
        #pragma unroll
        for (int k = 0; k < 8; ++k) acc += red[k];
        atomicAdd(&ws[WS_NUM], acc);
    }
}

// ---------------------------------------------------------------------------
// finalize: loss = -(num / B) / max(total_weight, 1e-8)
// ---------------------------------------------------------------------------
__global__ void finalize_kernel(const float* __restrict__ ws,
                                float* __restrict__ out) {
    const float tw = fmaxf(ws[WS_TW], 1e-8f);
    out[0] = -ws[WS_NUM] / ((float)NB * tw);
}

extern "C" void kernel_launch(void* const* d_in, const int* in_sizes, int n_in,
                              void* d_out, int out_size, void* d_ws, size_t ws_size,
                              hipStream_t stream) {
    const float* P    = (const float*)d_in[0];
    const float* dhw  = (const float*)d_in[1];
    const float* derr = (const float*)d_in[2];
    const int*   prs  = (const int*)d_in[3];
    const float* wts  = (const float*)d_in[4];
    float* ws  = (float*)d_ws;
    float* out = (float*)d_out;

    hipMemsetAsync(ws, 0, (WS_NUM + 1) * sizeof(float), stream);
    prep_kernel<<<128, 256, 0, stream>>>(P, dhw, derr, prs, wts, ws);
    batch_kernel<<<NB * 8, 512, 0, stream>>>(ws, ws);
    finalize_kernel<<<1, 1, 0, stream>>>(ws, out);
}

// Round 7
// 28.384 us; speedup vs baseline: 1.1864x; 1.1864x over previous
//
#include <hip/hip_runtime.h>

// Problem constants
#define NB 64
#define NL 128
#define NQ 128
#define NE 16384

// ws float layout
#define WS_W     0         // [i][j] row-major fp32 W (edge-weight scatter target)
#define WS_TWP   16384     // 64 per-block total-weight partials
#define WS_PART  16448     // 512 per-block numerator partials
// ws ushort layout (bf16 operand arrays), offsets in ushorts from ws base
#define US_ATB  33920                    // [q][p] A_fid^T bf16 (byte off 67840, 16B aligned)
#define US_PB   (US_ATB + 16384)         // [b][i][k] P bf16 plain, 64*16384
#define US_PTB  (US_PB + NB * 16384)     // [b][q][j] P bf16 transposed, 64*16384

using short8 = __attribute__((ext_vector_type(8))) short;  // 8 bf16
using f32x4  = __attribute__((ext_vector_type(4))) float;

// fp32 -> bf16 bits, round-to-nearest-even
__device__ inline unsigned short f2bf(float f) {
    const unsigned u = __float_as_uint(f);
    return (unsigned short)((u + 0x7fffu + ((u >> 16) & 1u)) >> 16);
}

__device__ inline short8 pack8(float4 a, float4 b) {
    short8 r;
    r[0] = f2bf(a.x); r[1] = f2bf(a.y); r[2] = f2bf(a.z); r[3] = f2bf(a.w);
    r[4] = f2bf(b.x); r[5] = f2bf(b.y); r[6] = f2bf(b.z); r[7] = f2bf(b.w);
    return r;
}

// ---------------------------------------------------------------------------
// prep, grid 128 x 256 (identical to round 6 except TW partial-slot write):
//  blocks 0..63  : convert P[b] to bf16 plain (PB) + LDS-transposed (PTB).
//  blocks 64..127: build ATB[q][p] bf16, scatter edge weights into fp32 W,
//                  write per-block total-weight partial to WS_TWP slot.
// ---------------------------------------------------------------------------
__global__ __launch_bounds__(256) void prep_kernel(const float* __restrict__ P,
                                                   const float* __restrict__ dhw,
                                                   const float* __restrict__ derr,
                                                   const int* __restrict__ pairs,
                                                   const float* __restrict__ wts,
                                                   float* __restrict__ ws) {
    const int t = threadIdx.x;
    unsigned short* us = (unsigned short*)ws;

    if (blockIdx.x < 64) {
        const int b = blockIdx.x;
        const float* __restrict__ Pb = P + b * 16384;
        unsigned short* __restrict__ PBb  = us + US_PB  + b * 16384;
        unsigned short* __restrict__ PTBb = us + US_PTB + b * 16384;

        __shared__ unsigned short T[128 * 132];   // row stride 132 (pad)

        #pragma unroll
        for (int r = 0; r < 16; ++r) {
            const int f = t + 256 * r;            // float4 idx [0,4096)
            const float4 v = ((const float4*)Pb)[f];
            ushort4 u;
            u.x = f2bf(v.x); u.y = f2bf(v.y); u.z = f2bf(v.z); u.w = f2bf(v.w);
            ((ushort4*)PBb)[f] = u;               // coalesced 8B stores
            const int i = f >> 5, c = (f & 31) * 4;
            *(ushort4*)&T[i * 132 + c] = u;
        }
        __syncthreads();

        // Emit transposed: PTB[q][j]; lanes span q -> conflict-free LDS reads
        #pragma unroll
        for (int r = 0; r < 8; ++r) {
            const int o  = t + 256 * r;           // short8 idx [0,2048)
            const int q  = o & 127;
            const int j0 = (o >> 7) * 8;
            short8 rd;
            #pragma unroll
            for (int d = 0; d < 8; ++d)
                rd[d] = (short)T[(j0 + d) * 132 + q];
            *(short8*)&PTBb[q * 128 + j0] = rd;
        }
    } else {
        const int blk = blockIdx.x - 64;               // [0,64)
        const int idx = blk * 256 + t;                 // [0, 16384)

        {   // ATB[q*128+p] = bf16( (dhw[p,q]==1) * max(1-derr[p,q],0) )
            const float hw = dhw[idx];
            const float er = derr[idx];
            const float a  = (hw == 1.0f) ? fmaxf(1.0f - er, 0.f) : 0.f;
            const int p = idx >> 7, q = idx & 127;
            us[US_ATB + q * 128 + p] = f2bf(a);
        }

        const int i = pairs[2 * idx];
        const int j = pairs[2 * idx + 1];
        const float w = wts[idx];
        atomicAdd(&ws[WS_W + i * 128 + j], w);     // distinct-address scatter: OK

        float s = w;
        #pragma unroll
        for (int off = 32; off; off >>= 1) s += __shfl_down(s, off, 64);
        __shared__ float red[4];
        const int lane = t & 63, wv = t >> 6;
        if (lane == 0) red[wv] = s;
        __syncthreads();
        if (t == 0)
            ws[WS_TWP + blk] = red[0] + red[1] + red[2] + red[3];  // plain store
    }
}

// ---------------------------------------------------------------------------
// batch (MFMA): identical to round 6 except the final write is a plain store
// to a distinct partial slot (no same-address atomic).
// block = (b, 16-row i-tile); 512 blocks x 512 threads (8 waves = 8 q-tiles).
// ---------------------------------------------------------------------------
__global__ __launch_bounds__(512, 4) void batch_kernel(const float* __restrict__ ws_c,
                                                       float* __restrict__ ws) {
    const int blk = blockIdx.x;            // 512 = 64 b * 8 i-tiles
    const int b   = blk >> 3;
    const int i0  = (blk & 7) * 16;
    const unsigned short* us = (const unsigned short*)ws_c;
    const unsigned short* __restrict__ PBb  = us + US_PB  + b * 16384;
    const unsigned short* __restrict__ PTBb = us + US_PTB + b * 16384;
    const unsigned short* __restrict__ ATB  = us + US_ATB;

    const int t    = threadIdx.x;
    const int wv   = t >> 6;               // 0..7 -> q-tile
    const int lane = t & 63;
    const int mrow = i0 + (lane & 15);
    const int kb   = (lane >> 4) * 8;
    const int ncol = wv * 16 + (lane & 15);

    const float* __restrict__ Wrow = ws_c + WS_W + mrow * 128;

    f32x4 accG = {0.f, 0.f, 0.f, 0.f};
    f32x4 accY = {0.f, 0.f, 0.f, 0.f};
    #pragma unroll
    for (int kk = 0; kk < 4; ++kk) {
        const int k0 = kk * 32 + kb;
        const short8 wa = pack8(*(const float4*)&Wrow[k0],
                                *(const float4*)&Wrow[k0 + 4]);
        const short8 gb = *(const short8*)&PTBb[ncol * 128 + k0];
        const short8 pa = *(const short8*)&PBb[mrow * 128 + k0];
        const short8 yb = *(const short8*)&ATB[ncol * 128 + k0];
        accG = __builtin_amdgcn_mfma_f32_16x16x32_bf16(wa, gb, accG, 0, 0, 0);
        accY = __builtin_amdgcn_mfma_f32_16x16x32_bf16(pa, yb, accY, 0, 0, 0);
    }

    float s = accG[0] * accY[0] + accG[1] * accY[1]
            + accG[2] * accY[2] + accG[3] * accY[3];

    #pragma unroll
    for (int off = 32; off; off >>= 1) s += __shfl_down(s, off, 64);
    __shared__ float red[8];
    if (lane == 0) red[wv] = s;
    __syncthreads();
    if (t == 0) {
        float acc = 0.f;
        #pragma unroll
        for (int k = 0; k < 8; ++k) acc += red[k];
        ws[WS_PART + blk] = acc;           // plain store, distinct slot
    }
}

// ---------------------------------------------------------------------------
// finalize: 1 block x 512 threads. Tree-reduce 512 numerator partials and
// 64 total-weight partials; loss = -(num / B) / max(tw, 1e-8).
// ---------------------------------------------------------------------------
__global__ __launch_bounds__(512) void finalize_kernel(const float* __restrict__ ws,
                                                       float* __restrict__ out) {
    const int t = threadIdx.x, lane = t & 63, wv = t >> 6;
    float n = ws[WS_PART + t];
    float w = (t < 64) ? ws[WS_TWP + t] : 0.f;
    #pragma unroll
    for (int off = 32; off; off >>= 1) {
        n += __shfl_down(n, off, 64);
        w += __shfl_down(w, off, 64);
    }
    __shared__ float rn[8], rw[8];
    if (lane == 0) { rn[wv] = n; rw[wv] = w; }
    __syncthreads();
    if (t == 0) {
        float num = 0.f, tw = 0.f;
        #pragma unroll
        for (int k = 0; k < 8; ++k) { num += rn[k]; tw += rw[k]; }
        out[0] = -num / ((float)NB * fmaxf(tw, 1e-8f));
    }
}

extern "C" void kernel_launch(void* const* d_in, const int* in_sizes, int n_in,
                              void* d_out, int out_size, void* d_ws, size_t ws_size,
                              hipStream_t stream) {
    const float* P    = (const float*)d_in[0];
    const float* dhw  = (const float*)d_in[1];
    const float* derr = (const float*)d_in[2];
    const int*   prs  = (const int*)d_in[3];
    const float* wts  = (const float*)d_in[4];
    float* ws  = (float*)d_ws;
    float* out = (float*)d_out;

    hipMemsetAsync(ws, 0, NL * NQ * sizeof(float), stream);   // zero W only
    prep_kernel<<<128, 256, 0, stream>>>(P, dhw, derr, prs, wts, ws);
    batch_kernel<<<NB * 8, 512, 0, stream>>>(ws, ws);
    finalize_kernel<<<1, 512, 0, stream>>>(ws, out);
}